// Round 12
// baseline (134.276 us; speedup 1.0000x reference)
//
#include <hip/hip_runtime.h>
#include <math.h>

#define NB 4
#define CC 256
#define CO 32
#define NN 4096
#define MU 320   // concat projection rows: 32 q + 32 k + 256 v
#define LOG2E 1.44269504088896f

typedef __attribute__((ext_vector_type(4))) float f4;
typedef __attribute__((ext_vector_type(8))) short s8;          // 8 bf16 MFMA frag
typedef __attribute__((ext_vector_type(8))) unsigned short us8;
typedef __attribute__((ext_vector_type(2))) unsigned int u2;
typedef __attribute__((ext_vector_type(4))) unsigned int u4i;

// fp32 -> bf16 (RNE), scalar fallback
__device__ __forceinline__ unsigned short f2bf(float f) {
    unsigned int u = __float_as_uint(f);
    u = (u + 0x7FFFu + ((u >> 16) & 1u)) >> 16;
    return (unsigned short)u;
}
// HW packed convert: dst = {bf16(lo), bf16(hi)}
__device__ __forceinline__ unsigned int cvtpk(float lo, float hi) {
    unsigned int r;
    asm("v_cvt_pk_bf16_f32 %0, %1, %2" : "=v"(r) : "v"(lo), "v"(hi));
    return r;
}
// XOR-swizzled byte offset within a 128B-row LDS tile (verified round 8)
__device__ __forceinline__ int swz128(int row, int colByte) {
    return row * 128 + (colByte ^ ((row & 7) << 4));
}

union s8u4 { s8 s; u4i u; };

// ---------------------------------------------------------------------------
// prepw: grid 80. Wb[320][256] bf16, fb[320] f32.  (round-11 passing)
// ---------------------------------------------------------------------------
__global__ __launch_bounds__(256) void prepw_kernel(
    const float* __restrict__ Wq, const float* __restrict__ bq,
    const float* __restrict__ Wk, const float* __restrict__ bk,
    const float* __restrict__ Wv, const float* __restrict__ bv,
    unsigned short* __restrict__ Wb, float* __restrict__ fb)
{
    const int t = threadIdx.x;
    #pragma unroll
    for (int i = 0; i < 4; ++i) {
        const int e = blockIdx.x * 1024 + i * 256 + t;
        const int u = e >> 8, c = e & 255;
        float val = (u < 32) ? Wq[u * 256 + c]
                  : (u < 64) ? Wk[(u - 32) * 256 + c]
                             : Wv[(u - 64) * 256 + c];
        Wb[e] = f2bf(val);
    }
    if (blockIdx.x == 0) {
        for (int u = t; u < MU; u += 256)
            fb[u] = (u < 32) ? bq[u] : (u < 64) ? bk[u - 32] : bv[u - 64];
    }
}

// ---------------------------------------------------------------------------
// projf: fused transpose + MFMA projection (round-11 passing, unchanged).
// ---------------------------------------------------------------------------
__global__ __launch_bounds__(256) void projf_kernel(
    const float* __restrict__ x, const unsigned short* __restrict__ Wb,
    const float* __restrict__ fb,
    unsigned short* __restrict__ qb, unsigned short* __restrict__ kb,
    unsigned short* __restrict__ vtb)
{
    __shared__ float xl[32][260];

    const int t   = threadIdx.x;
    const int b   = blockIdx.x >> 7;
    const int nbl = blockIdx.x & 127;
    const int n0  = nbl * 32;

    {
        const int nl = t & 7;
        const int c8 = t >> 3;
        #pragma unroll
        for (int pass = 0; pass < 8; ++pass) {
            const int c = c8 + pass * 32;
            f4 xv = *reinterpret_cast<const f4*>(x + ((size_t)(b * CC + c)) * NN + n0 + nl * 4);
            #pragma unroll
            for (int j = 0; j < 4; ++j) xl[nl * 4 + j][c] = xv[j];
        }
    }
    __syncthreads();

    const int w    = t >> 6;
    const int l    = t & 63;
    const int l15  = l & 15;
    const int g4   = l >> 4;
    const int nw   = w & 1;
    const int uw   = w >> 1;
    const int nloc = nw * 16 + l15;
    const int n    = n0 + nloc;

    s8 bfr[8];
    #pragma unroll
    for (int kk = 0; kk < 8; ++kk) {
        f4 a  = *reinterpret_cast<const f4*>(&xl[nloc][kk * 32 + g4 * 8]);
        f4 c2 = *reinterpret_cast<const f4*>(&xl[nloc][kk * 32 + g4 * 8 + 4]);
        s8u4 tmp;
        tmp.u = (u4i){ cvtpk(a[0], a[1]), cvtpk(a[2], a[3]),
                       cvtpk(c2[0], c2[1]), cvtpk(c2[2], c2[3]) };
        bfr[kk] = tmp.s;
    }

    const f4 z = {0.f, 0.f, 0.f, 0.f};
    unsigned short* qrow = qb + ((size_t)(b * NN + n)) * CO;
    unsigned short* krow = kb + ((size_t)(b * NN + n)) * CO;

    #pragma unroll
    for (int i = 0; i < 10; ++i) {
        const int u0 = (uw * 10 + i) * 16;
        f4 acc = z;
        #pragma unroll
        for (int kk = 0; kk < 8; ++kk) {
            s8 af = *reinterpret_cast<const s8*>(Wb + (size_t)(u0 + l15) * CC + kk * 32 + g4 * 8);
            acc = __builtin_amdgcn_mfma_f32_16x16x32_bf16(af, bfr[kk], acc, 0, 0, 0);
        }
        f4 bias4 = *reinterpret_cast<const f4*>(fb + u0 + g4 * 4);
        if (u0 < 32) {
            u2 pw = { cvtpk((acc[0] + bias4[0]) * LOG2E, (acc[1] + bias4[1]) * LOG2E),
                      cvtpk((acc[2] + bias4[2]) * LOG2E, (acc[3] + bias4[3]) * LOG2E) };
            *reinterpret_cast<u2*>(qrow + u0 + g4 * 4) = pw;
        } else if (u0 < 64) {
            u2 pw = { cvtpk(acc[0] + bias4[0], acc[1] + bias4[1]),
                      cvtpk(acc[2] + bias4[2], acc[3] + bias4[3]) };
            *reinterpret_cast<u2*>(krow + (u0 - 32) + g4 * 4) = pw;
        } else {
            const int cbase = u0 - 64 + g4 * 4;
            #pragma unroll
            for (int r = 0; r < 4; ++r)
                vtb[((size_t)(b * CC + cbase + r)) * NN + n] = f2bf(acc[r] + bias4[r]);
        }
    }
}

// ---------------------------------------------------------------------------
// colstats + vscale (round-11 passing, unchanged): grid 1024.
// ---------------------------------------------------------------------------
__global__ __launch_bounds__(256) void colstats_kernel(
    const unsigned short* __restrict__ qb, const unsigned short* __restrict__ kb,
    unsigned short* __restrict__ vtb)
{
    __shared__ float red[4][16];
    __shared__ float civl[16];

    const int t   = threadIdx.x;
    const int b   = blockIdx.x >> 8;
    const int mb  = blockIdx.x & 255;
    const int l   = t & 63;
    const int w   = t >> 6;
    const int l15 = l & 15;
    const int g4  = l >> 4;
    const int m   = mb * 16 + l15;

    const unsigned short* qbB = qb + (size_t)b * NN * CO;
    s8 kfrag = *reinterpret_cast<const s8*>(kb + ((size_t)b * NN + m) * CO + g4 * 8);

    const f4 z = {0.f, 0.f, 0.f, 0.f};
    float ssum = 0.f;

    const int nbeg = w * 1024, nend = nbeg + 1024;
    for (int n0 = nbeg; n0 < nend; n0 += 32) {
        s8 a0 = *reinterpret_cast<const s8*>(qbB + (size_t)(n0 + l15) * CO + g4 * 8);
        s8 a1 = *reinterpret_cast<const s8*>(qbB + (size_t)(n0 + 16 + l15) * CO + g4 * 8);
        f4 d0 = __builtin_amdgcn_mfma_f32_16x16x32_bf16(a0, kfrag, z, 0, 0, 0);
        f4 d1 = __builtin_amdgcn_mfma_f32_16x16x32_bf16(a1, kfrag, z, 0, 0, 0);
        #pragma unroll
        for (int r = 0; r < 4; ++r) ssum += exp2f(d0[r]) + exp2f(d1[r]);
    }

    ssum += __shfl_xor(ssum, 16);
    ssum += __shfl_xor(ssum, 32);
    if (l < 16) red[w][l15] = ssum;
    __syncthreads();
    if (w == 0 && l < 16)
        civl[l15] = 1.0f / (red[0][l15] + red[1][l15] + red[2][l15] + red[3][l15]);
    __syncthreads();

    unsigned short* vp = vtb + ((size_t)(b * CC + t)) * NN + mb * 16;
    #pragma unroll
    for (int i = 0; i < 2; ++i) {
        us8 vv = *reinterpret_cast<const us8*>(vp + i * 8);
        u4i o;
        #pragma unroll
        for (int e2 = 0; e2 < 4; ++e2) {
            float f0 = __uint_as_float((unsigned int)vv[2 * e2]     << 16) * civl[i * 8 + 2 * e2];
            float f1 = __uint_as_float((unsigned int)vv[2 * e2 + 1] << 16) * civl[i * 8 + 2 * e2 + 1];
            o[e2] = cvtpk(f0, f1);
        }
        *reinterpret_cast<u4i*>(vp + i * 8) = o;
    }
}

// ---------------------------------------------------------------------------
// attn: out[n,c] = sum_m exp2(S[n,m]) * v'[m,c].
// NEW: block tile 128n x 128c, 512 threads / 8 waves, grid 256 (1 block/CU).
//   S: wave w owns n-rows w*16..+16 entirely: 4 swapped S-MFMA (j=0..3),
//      16 exp2, 8 cvt_pk, 4 b64 P-writes.
//   V: 512 threads stage 32B each into vlds[128c][64m].
//   PV: wave quadrant 32n x 64c (wr = w>>1, wc = w&1), acc[2][4]:
//      per ksl 6 b128 reads -> 8 MFMA (0.75 KB/MFMA; was 1.0).
// LDS/CU/tile: 128 KB (was 176).  Double-buffered, swizzled, setprio.
// ---------------------------------------------------------------------------
__global__ __launch_bounds__(512) void attn_kernel(
    const unsigned short* __restrict__ qb, const unsigned short* __restrict__ kb,
    const unsigned short* __restrict__ vtb, float* __restrict__ out)
{
    __shared__ __align__(16) char plds[2][128 * 128];   // P tile  [n][m] bf16, swizzled
    __shared__ __align__(16) char vlds[2][128 * 128];   // vT tile [c][m] bf16, swizzled

    const int t    = threadIdx.x;
    const int bid  = blockIdx.x;
    const int cblk = bid & 1;
    const int nblk = (bid >> 1) & 31;
    const int b    = bid >> 6;
    const int n0   = nblk * 128;
    const int c0   = cblk * 128;
    const int l    = t & 63;
    const int w    = t >> 6;        // 0..7
    const int l15  = l & 15;
    const int g4   = l >> 4;
    const int wr   = w >> 1;        // PV n-quarter (32n)
    const int wc   = w & 1;         // PV c-half (64c)

    const unsigned short* qbB = qb  + (size_t)b * NN * CO;
    const unsigned short* kbB = kb  + (size_t)b * NN * CO;
    const unsigned short* vtB = vtb + (size_t)b * CC * NN;

    // wave's 16 S-rows (B-operand of swapped MFMA)
    s8 qfrag = *reinterpret_cast<const s8*>(qbB + (size_t)(n0 + w * 16 + l15) * CO + g4 * 8);

    s8 kreg[4];
    s8 vs[2];
    const int vrow = t >> 2;           // c-local row staged by this thread (0..127)
    const int q4   = t & 3;            // m-quarter (16 m = 32B)

    auto loadnext = [&](int mP) {
        #pragma unroll
        for (int j = 0; j < 4; ++j)
            kreg[j] = *reinterpret_cast<const s8*>(kbB + (size_t)(mP + j * 16 + l15) * CO + g4 * 8);
        const unsigned short* vsrc = vtB + (size_t)(c0 + vrow) * NN + mP + q4 * 16;
        vs[0] = *reinterpret_cast<const s8*>(vsrc);
        vs[1] = *reinterpret_cast<const s8*>(vsrc + 8);
    };

    const f4 z = {0.f, 0.f, 0.f, 0.f};

    auto stage = [&](int buf) {
        // swapped S: d = mfma(K_rows(m), Q_rows(n)):
        //   lane (l15,g4): n = w*16+l15, m = j*16 + g4*4 + r
        #pragma unroll
        for (int j = 0; j < 4; ++j) {
            f4 d = __builtin_amdgcn_mfma_f32_16x16x32_bf16(kreg[j], qfrag, z, 0, 0, 0);
            u2 pw = { cvtpk(exp2f(d[0]), exp2f(d[1])),
                      cvtpk(exp2f(d[2]), exp2f(d[3])) };
            *reinterpret_cast<u2*>(plds[buf] + swz128(w * 16 + l15, j * 32 + g4 * 8)) = pw;
        }
        *reinterpret_cast<s8*>(vlds[buf] + swz128(vrow, q4 * 32))      = vs[0];
        *reinterpret_cast<s8*>(vlds[buf] + swz128(vrow, q4 * 32 + 16)) = vs[1];
    };

    f4 acc[2][4];
    #pragma unroll
    for (int a = 0; a < 2; ++a)
        #pragma unroll
        for (int c = 0; c < 4; ++c) acc[a][c] = z;

    loadnext(0);
    stage(0);
    loadnext(64);
    __syncthreads();

    for (int i = 0; i < 64; ++i) {
        const int cur = i & 1;
        if (i < 63) {
            stage(cur ^ 1);
            if (i < 62) loadnext((i + 2) * 64);
        }
        #pragma unroll
        for (int ksl = 0; ksl < 2; ++ksl) {
            s8 pa[2], vb[4];
            #pragma unroll
            for (int a = 0; a < 2; ++a)
                pa[a] = *reinterpret_cast<const s8*>(
                    plds[cur] + swz128(wr * 32 + a * 16 + l15, ksl * 64 + g4 * 16));
            #pragma unroll
            for (int c = 0; c < 4; ++c)
                vb[c] = *reinterpret_cast<const s8*>(
                    vlds[cur] + swz128(wc * 64 + c * 16 + l15, ksl * 64 + g4 * 16));
            __builtin_amdgcn_s_setprio(1);
            #pragma unroll
            for (int a = 0; a < 2; ++a)
                #pragma unroll
                for (int c = 0; c < 4; ++c)
                    acc[a][c] = __builtin_amdgcn_mfma_f32_16x16x32_bf16(pa[a], vb[c], acc[a][c], 0, 0, 0);
            __builtin_amdgcn_s_setprio(0);
        }
        __syncthreads();
    }

    // D layout: col = lane&15 (c), row = g4*4 + r (n)
    #pragma unroll
    for (int a = 0; a < 2; ++a) {
        const int row = n0 + wr * 32 + a * 16 + g4 * 4;
        #pragma unroll
        for (int c = 0; c < 4; ++c) {
            const int col = c0 + wc * 64 + c * 16 + l15;
            #pragma unroll
            for (int r = 0; r < 4; ++r)
                out[((size_t)(b * NN + row + r)) * CC + col] = acc[a][c][r];
        }
    }
}

extern "C" void kernel_launch(void* const* d_in, const int* in_sizes, int n_in,
                              void* d_out, int out_size, void* d_ws, size_t ws_size,
                              hipStream_t stream)
{
    const float* x  = (const float*)d_in[0];
    const float* Wq = (const float*)d_in[1];
    const float* bq = (const float*)d_in[2];
    const float* Wk = (const float*)d_in[3];
    const float* bk = (const float*)d_in[4];
    const float* Wv = (const float*)d_in[5];
    const float* bv = (const float*)d_in[6];
    float* out = (float*)d_out;

    // ws layout: qb(1MB) | kb(1MB) | vtb(8MB) | Wb(160KB) | fb(1.25KB)
    unsigned short* qb  = (unsigned short*)d_ws;
    unsigned short* kb  = qb + (size_t)NB * NN * CO;
    unsigned short* vtb = kb + (size_t)NB * NN * CO;
    unsigned short* Wb  = vtb + (size_t)NB * CC * NN;
    float*          fb  = (float*)(Wb + (size_t)MU * CC);

    prepw_kernel<<<dim3(80), dim3(256), 0, stream>>>(Wq, bq, Wk, bk, Wv, bv, Wb, fb);
    projf_kernel<<<dim3(512), dim3(256), 0, stream>>>(x, Wb, fb, qb, kb, vtb);
    colstats_kernel<<<dim3(1024), dim3(256), 0, stream>>>(qb, kb, vtb);
    attn_kernel<<<dim3(256), dim3(512), 0, stream>>>(qb, kb, vtb, out);
}

// Round 13
// 127.216 us; speedup vs baseline: 1.0555x; 1.0555x over previous
//
#include <hip/hip_runtime.h>
#include <math.h>

#define NB 4
#define CC 256
#define CO 32
#define NN 4096
#define MU 320   // concat projection rows: 32 q + 32 k + 256 v
#define LOG2E 1.44269504088896f

typedef __attribute__((ext_vector_type(4))) float f4;
typedef __attribute__((ext_vector_type(8))) short s8;          // 8 bf16 MFMA frag
typedef __attribute__((ext_vector_type(8))) unsigned short us8;
typedef __attribute__((ext_vector_type(2))) unsigned int u2;
typedef __attribute__((ext_vector_type(4))) unsigned int u4i;

// fp32 -> bf16 (RNE), scalar fallback
__device__ __forceinline__ unsigned short f2bf(float f) {
    unsigned int u = __float_as_uint(f);
    u = (u + 0x7FFFu + ((u >> 16) & 1u)) >> 16;
    return (unsigned short)u;
}
// HW packed convert: dst = {bf16(lo), bf16(hi)}
__device__ __forceinline__ unsigned int cvtpk(float lo, float hi) {
    unsigned int r;
    asm("v_cvt_pk_bf16_f32 %0, %1, %2" : "=v"(r) : "v"(lo), "v"(hi));
    return r;
}
// XOR-swizzled byte offset within a 128B-row LDS tile (verified round 8)
__device__ __forceinline__ int swz128(int row, int colByte) {
    return row * 128 + (colByte ^ ((row & 7) << 4));
}

union s8u4 { s8 s; u4i u; };

// ---------------------------------------------------------------------------
// prepw: grid 80. Wb[320][256] bf16, fb[320] f32.  (round-12 passing)
// ---------------------------------------------------------------------------
__global__ __launch_bounds__(256) void prepw_kernel(
    const float* __restrict__ Wq, const float* __restrict__ bq,
    const float* __restrict__ Wk, const float* __restrict__ bk,
    const float* __restrict__ Wv, const float* __restrict__ bv,
    unsigned short* __restrict__ Wb, float* __restrict__ fb)
{
    const int t = threadIdx.x;
    #pragma unroll
    for (int i = 0; i < 4; ++i) {
        const int e = blockIdx.x * 1024 + i * 256 + t;
        const int u = e >> 8, c = e & 255;
        float val = (u < 32) ? Wq[u * 256 + c]
                  : (u < 64) ? Wk[(u - 32) * 256 + c]
                             : Wv[(u - 64) * 256 + c];
        Wb[e] = f2bf(val);
    }
    if (blockIdx.x == 0) {
        for (int u = t; u < MU; u += 256)
            fb[u] = (u < 32) ? bq[u] : (u < 64) ? bk[u - 32] : bv[u - 64];
    }
}

// ---------------------------------------------------------------------------
// projf: fused transpose + MFMA projection (round-12 passing, unchanged).
// ---------------------------------------------------------------------------
__global__ __launch_bounds__(256) void projf_kernel(
    const float* __restrict__ x, const unsigned short* __restrict__ Wb,
    const float* __restrict__ fb,
    unsigned short* __restrict__ qb, unsigned short* __restrict__ kb,
    unsigned short* __restrict__ vtb)
{
    __shared__ float xl[32][260];

    const int t   = threadIdx.x;
    const int b   = blockIdx.x >> 7;
    const int nbl = blockIdx.x & 127;
    const int n0  = nbl * 32;

    {
        const int nl = t & 7;
        const int c8 = t >> 3;
        #pragma unroll
        for (int pass = 0; pass < 8; ++pass) {
            const int c = c8 + pass * 32;
            f4 xv = *reinterpret_cast<const f4*>(x + ((size_t)(b * CC + c)) * NN + n0 + nl * 4);
            #pragma unroll
            for (int j = 0; j < 4; ++j) xl[nl * 4 + j][c] = xv[j];
        }
    }
    __syncthreads();

    const int w    = t >> 6;
    const int l    = t & 63;
    const int l15  = l & 15;
    const int g4   = l >> 4;
    const int nw   = w & 1;
    const int uw   = w >> 1;
    const int nloc = nw * 16 + l15;
    const int n    = n0 + nloc;

    s8 bfr[8];
    #pragma unroll
    for (int kk = 0; kk < 8; ++kk) {
        f4 a  = *reinterpret_cast<const f4*>(&xl[nloc][kk * 32 + g4 * 8]);
        f4 c2 = *reinterpret_cast<const f4*>(&xl[nloc][kk * 32 + g4 * 8 + 4]);
        s8u4 tmp;
        tmp.u = (u4i){ cvtpk(a[0], a[1]), cvtpk(a[2], a[3]),
                       cvtpk(c2[0], c2[1]), cvtpk(c2[2], c2[3]) };
        bfr[kk] = tmp.s;
    }

    const f4 z = {0.f, 0.f, 0.f, 0.f};
    unsigned short* qrow = qb + ((size_t)(b * NN + n)) * CO;
    unsigned short* krow = kb + ((size_t)(b * NN + n)) * CO;

    #pragma unroll
    for (int i = 0; i < 10; ++i) {
        const int u0 = (uw * 10 + i) * 16;
        f4 acc = z;
        #pragma unroll
        for (int kk = 0; kk < 8; ++kk) {
            s8 af = *reinterpret_cast<const s8*>(Wb + (size_t)(u0 + l15) * CC + kk * 32 + g4 * 8);
            acc = __builtin_amdgcn_mfma_f32_16x16x32_bf16(af, bfr[kk], acc, 0, 0, 0);
        }
        f4 bias4 = *reinterpret_cast<const f4*>(fb + u0 + g4 * 4);
        if (u0 < 32) {
            u2 pw = { cvtpk((acc[0] + bias4[0]) * LOG2E, (acc[1] + bias4[1]) * LOG2E),
                      cvtpk((acc[2] + bias4[2]) * LOG2E, (acc[3] + bias4[3]) * LOG2E) };
            *reinterpret_cast<u2*>(qrow + u0 + g4 * 4) = pw;
        } else if (u0 < 64) {
            u2 pw = { cvtpk(acc[0] + bias4[0], acc[1] + bias4[1]),
                      cvtpk(acc[2] + bias4[2], acc[3] + bias4[3]) };
            *reinterpret_cast<u2*>(krow + (u0 - 32) + g4 * 4) = pw;
        } else {
            const int cbase = u0 - 64 + g4 * 4;
            #pragma unroll
            for (int r = 0; r < 4; ++r)
                vtb[((size_t)(b * CC + cbase + r)) * NN + n] = f2bf(acc[r] + bias4[r]);
        }
    }
}

// ---------------------------------------------------------------------------
// colstats + vscale (round-12 passing, unchanged): grid 1024.
// ---------------------------------------------------------------------------
__global__ __launch_bounds__(256) void colstats_kernel(
    const unsigned short* __restrict__ qb, const unsigned short* __restrict__ kb,
    unsigned short* __restrict__ vtb)
{
    __shared__ float red[4][16];
    __shared__ float civl[16];

    const int t   = threadIdx.x;
    const int b   = blockIdx.x >> 8;
    const int mb  = blockIdx.x & 255;
    const int l   = t & 63;
    const int w   = t >> 6;
    const int l15 = l & 15;
    const int g4  = l >> 4;
    const int m   = mb * 16 + l15;

    const unsigned short* qbB = qb + (size_t)b * NN * CO;
    s8 kfrag = *reinterpret_cast<const s8*>(kb + ((size_t)b * NN + m) * CO + g4 * 8);

    const f4 z = {0.f, 0.f, 0.f, 0.f};
    float ssum = 0.f;

    const int nbeg = w * 1024, nend = nbeg + 1024;
    for (int n0 = nbeg; n0 < nend; n0 += 32) {
        s8 a0 = *reinterpret_cast<const s8*>(qbB + (size_t)(n0 + l15) * CO + g4 * 8);
        s8 a1 = *reinterpret_cast<const s8*>(qbB + (size_t)(n0 + 16 + l15) * CO + g4 * 8);
        f4 d0 = __builtin_amdgcn_mfma_f32_16x16x32_bf16(a0, kfrag, z, 0, 0, 0);
        f4 d1 = __builtin_amdgcn_mfma_f32_16x16x32_bf16(a1, kfrag, z, 0, 0, 0);
        #pragma unroll
        for (int r = 0; r < 4; ++r) ssum += exp2f(d0[r]) + exp2f(d1[r]);
    }

    ssum += __shfl_xor(ssum, 16);
    ssum += __shfl_xor(ssum, 32);
    if (l < 16) red[w][l15] = ssum;
    __syncthreads();
    if (w == 0 && l < 16)
        civl[l15] = 1.0f / (red[0][l15] + red[1][l15] + red[2][l15] + red[3][l15]);
    __syncthreads();

    unsigned short* vp = vtb + ((size_t)(b * CC + t)) * NN + mb * 16;
    #pragma unroll
    for (int i = 0; i < 2; ++i) {
        us8 vv = *reinterpret_cast<const us8*>(vp + i * 8);
        u4i o;
        #pragma unroll
        for (int e2 = 0; e2 < 4; ++e2) {
            float f0 = __uint_as_float((unsigned int)vv[2 * e2]     << 16) * civl[i * 8 + 2 * e2];
            float f1 = __uint_as_float((unsigned int)vv[2 * e2 + 1] << 16) * civl[i * 8 + 2 * e2 + 1];
            o[e2] = cvtpk(f0, f1);
        }
        *reinterpret_cast<u4i*>(vp + i * 8) = o;
    }
}

// ---------------------------------------------------------------------------
// attn: out[n,c] = sum_m exp2(S[n,m]) * v'[m,c]  (v' pre-scaled, q pre-log2e).
// Round-11 geometry (64n x 128c, 512 thr / 8 waves, grid 512, 2 blocks/CU),
// VALU-stripped: manual unroll-by-2 with LITERAL buffer indices, all 12
// swizzled LDS offsets precomputed (loop-invariant), incremental global
// pointers.  PV: load all 8 frags then one setprio-wrapped 8-MFMA cluster.
// ---------------------------------------------------------------------------
__global__ __launch_bounds__(512) void attn_kernel(
    const unsigned short* __restrict__ qb, const unsigned short* __restrict__ kb,
    const unsigned short* __restrict__ vtb, float* __restrict__ out)
{
    __shared__ __align__(16) char plds[2][64 * 128];    // P tile  [n][m] bf16, swizzled
    __shared__ __align__(16) char vlds[2][128 * 128];   // vT tile [c][m] bf16, swizzled

    const int t    = threadIdx.x;
    const int bid  = blockIdx.x;
    const int cblk = bid & 1;
    const int nblk = (bid >> 1) & 63;
    const int b    = bid >> 7;
    const int n0   = nblk * 64;
    const int c0   = cblk * 128;
    const int l    = t & 63;
    const int w    = t >> 6;        // 0..7
    const int l15  = l & 15;
    const int g4   = l >> 4;
    const int g    = w >> 1;        // S n-group (16 rows)
    const int p    = w & 1;         // S j-pair
    const int wrn  = w >> 2;        // PV n-half
    const int wcq  = w & 3;         // PV c-quarter

    const unsigned short* qbB = qb  + (size_t)b * NN * CO;
    const unsigned short* kbB = kb  + (size_t)b * NN * CO;
    const unsigned short* vtB = vtb + (size_t)b * CC * NN;

    // wave's 16 S-rows (B-operand of swapped MFMA)
    s8 qfrag = *reinterpret_cast<const s8*>(qbB + (size_t)(n0 + g * 16 + l15) * CO + g4 * 8);

    // ---- precomputed loop-invariant LDS byte offsets ----
    const int vrow = t >> 2;            // 0..127
    const int q4   = t & 3;
    const int pw0  = swz128(g * 16 + l15, (2 * p) * 32 + g4 * 8);
    const int pw1  = swz128(g * 16 + l15, (2 * p + 1) * 32 + g4 * 8);
    const int vw0  = swz128(vrow, q4 * 32);
    const int vw1  = swz128(vrow, q4 * 32 + 16);
    const int prk0a0 = swz128(wrn * 32 +      l15,      g4 * 16);
    const int prk0a1 = swz128(wrn * 32 + 16 + l15,      g4 * 16);
    const int prk1a0 = swz128(wrn * 32 +      l15, 64 + g4 * 16);
    const int prk1a1 = swz128(wrn * 32 + 16 + l15, 64 + g4 * 16);
    const int vrk0c0 = swz128(wcq * 32 +      l15,      g4 * 16);
    const int vrk0c1 = swz128(wcq * 32 + 16 + l15,      g4 * 16);
    const int vrk1c0 = swz128(wcq * 32 +      l15, 64 + g4 * 16);
    const int vrk1c1 = swz128(wcq * 32 + 16 + l15, 64 + g4 * 16);

    // ---- incremental global pointers ----
    const unsigned short* kp = kbB + (size_t)((2 * p) * 16 + l15) * CO + g4 * 8;
    const unsigned short* vp = vtB + (size_t)(c0 + vrow) * NN + q4 * 16;

    s8 kreg[2];
    s8 vs[2];
    const f4 z = {0.f, 0.f, 0.f, 0.f};

#define LOADNEXT() do { \
        kreg[0] = *reinterpret_cast<const s8*>(kp); \
        kreg[1] = *reinterpret_cast<const s8*>(kp + 16 * CO); \
        vs[0]   = *reinterpret_cast<const s8*>(vp); \
        vs[1]   = *reinterpret_cast<const s8*>(vp + 8); \
        kp += 64 * CO; vp += 64; \
    } while (0)

#define STAGE(BUF) do { \
        f4 d0 = __builtin_amdgcn_mfma_f32_16x16x32_bf16(kreg[0], qfrag, z, 0, 0, 0); \
        f4 d1 = __builtin_amdgcn_mfma_f32_16x16x32_bf16(kreg[1], qfrag, z, 0, 0, 0); \
        u2 pq0 = { cvtpk(exp2f(d0[0]), exp2f(d0[1])), cvtpk(exp2f(d0[2]), exp2f(d0[3])) }; \
        u2 pq1 = { cvtpk(exp2f(d1[0]), exp2f(d1[1])), cvtpk(exp2f(d1[2]), exp2f(d1[3])) }; \
        *reinterpret_cast<u2*>(plds[BUF] + pw0) = pq0; \
        *reinterpret_cast<u2*>(plds[BUF] + pw1) = pq1; \
        *reinterpret_cast<s8*>(vlds[BUF] + vw0) = vs[0]; \
        *reinterpret_cast<s8*>(vlds[BUF] + vw1) = vs[1]; \
    } while (0)

#define PVSTEP(BUF) do { \
        s8 pa00 = *reinterpret_cast<const s8*>(plds[BUF] + prk0a0); \
        s8 pa01 = *reinterpret_cast<const s8*>(plds[BUF] + prk0a1); \
        s8 pa10 = *reinterpret_cast<const s8*>(plds[BUF] + prk1a0); \
        s8 pa11 = *reinterpret_cast<const s8*>(plds[BUF] + prk1a1); \
        s8 vb00 = *reinterpret_cast<const s8*>(vlds[BUF] + vrk0c0); \
        s8 vb01 = *reinterpret_cast<const s8*>(vlds[BUF] + vrk0c1); \
        s8 vb10 = *reinterpret_cast<const s8*>(vlds[BUF] + vrk1c0); \
        s8 vb11 = *reinterpret_cast<const s8*>(vlds[BUF] + vrk1c1); \
        __builtin_amdgcn_s_setprio(1); \
        acc[0][0] = __builtin_amdgcn_mfma_f32_16x16x32_bf16(pa00, vb00, acc[0][0], 0, 0, 0); \
        acc[0][1] = __builtin_amdgcn_mfma_f32_16x16x32_bf16(pa00, vb01, acc[0][1], 0, 0, 0); \
        acc[1][0] = __builtin_amdgcn_mfma_f32_16x16x32_bf16(pa01, vb00, acc[1][0], 0, 0, 0); \
        acc[1][1] = __builtin_amdgcn_mfma_f32_16x16x32_bf16(pa01, vb01, acc[1][1], 0, 0, 0); \
        acc[0][0] = __builtin_amdgcn_mfma_f32_16x16x32_bf16(pa10, vb10, acc[0][0], 0, 0, 0); \
        acc[0][1] = __builtin_amdgcn_mfma_f32_16x16x32_bf16(pa10, vb11, acc[0][1], 0, 0, 0); \
        acc[1][0] = __builtin_amdgcn_mfma_f32_16x16x32_bf16(pa11, vb10, acc[1][0], 0, 0, 0); \
        acc[1][1] = __builtin_amdgcn_mfma_f32_16x16x32_bf16(pa11, vb11, acc[1][1], 0, 0, 0); \
        __builtin_amdgcn_s_setprio(0); \
    } while (0)

    f4 acc[2][2];
    acc[0][0] = z; acc[0][1] = z; acc[1][0] = z; acc[1][1] = z;

    // prologue: tile 0 -> buf0, prefetch tile 1
    LOADNEXT();
    STAGE(0);
    LOADNEXT();
    __syncthreads();

    for (int i = 0; i < 64; i += 2) {
        // ---- iter i: current buf 0 ----
        if (i < 63) {
            STAGE(1);
            if (i < 62) LOADNEXT();
        }
        PVSTEP(0);
        __syncthreads();
        // ---- iter i+1: current buf 1 ----
        if (i + 1 < 63) {
            STAGE(0);
            if (i + 1 < 62) LOADNEXT();
        }
        PVSTEP(1);
        __syncthreads();
    }

#undef LOADNEXT
#undef STAGE
#undef PVSTEP

    // D layout: col = lane&15 (c), row = g4*4 + r (n)
    #pragma unroll
    for (int a = 0; a < 2; ++a) {
        const int row = n0 + wrn * 32 + a * 16 + g4 * 4;
        #pragma unroll
        for (int c = 0; c < 2; ++c) {
            const int col = c0 + wcq * 32 + c * 16 + l15;
            #pragma unroll
            for (int r = 0; r < 4; ++r)
                out[((size_t)(b * NN + row + r)) * CC + col] = acc[a][c][r];
        }
    }
}

extern "C" void kernel_launch(void* const* d_in, const int* in_sizes, int n_in,
                              void* d_out, int out_size, void* d_ws, size_t ws_size,
                              hipStream_t stream)
{
    const float* x  = (const float*)d_in[0];
    const float* Wq = (const float*)d_in[1];
    const float* bq = (const float*)d_in[2];
    const float* Wk = (const float*)d_in[3];
    const float* bk = (const float*)d_in[4];
    const float* Wv = (const float*)d_in[5];
    const float* bv = (const float*)d_in[6];
    float* out = (float*)d_out;

    // ws layout: qb(1MB) | kb(1MB) | vtb(8MB) | Wb(160KB) | fb(1.25KB)
    unsigned short* qb  = (unsigned short*)d_ws;
    unsigned short* kb  = qb + (size_t)NB * NN * CO;
    unsigned short* vtb = kb + (size_t)NB * NN * CO;
    unsigned short* Wb  = vtb + (size_t)NB * CC * NN;
    float*          fb  = (float*)(Wb + (size_t)MU * CC);

    prepw_kernel<<<dim3(80), dim3(256), 0, stream>>>(Wq, bq, Wk, bk, Wv, bv, Wb, fb);
    projf_kernel<<<dim3(512), dim3(256), 0, stream>>>(x, Wb, fb, qb, kb, vtb);
    colstats_kernel<<<dim3(1024), dim3(256), 0, stream>>>(qb, kb, vtb);
    attn_kernel<<<dim3(512), dim3(512), 0, stream>>>(qb, kb, vtb, out);
}

// Round 17
// 122.324 us; speedup vs baseline: 1.0977x; 1.0400x over previous
//
#include <hip/hip_runtime.h>
#include <math.h>

#define NB 4
#define CC 256
#define CO 32
#define NN 4096
#define MU 320   // concat projection rows: 32 q + 32 k + 256 v
#define LOG2E 1.44269504088896f

typedef __attribute__((ext_vector_type(4))) float f4;
typedef __attribute__((ext_vector_type(8))) short s8;          // 8 bf16 MFMA frag
typedef __attribute__((ext_vector_type(8))) unsigned short us8;
typedef __attribute__((ext_vector_type(2))) unsigned int u2;
typedef __attribute__((ext_vector_type(4))) unsigned int u4i;

// fp32 -> bf16 (RNE), scalar fallback
__device__ __forceinline__ unsigned short f2bf(float f) {
    unsigned int u = __float_as_uint(f);
    u = (u + 0x7FFFu + ((u >> 16) & 1u)) >> 16;
    return (unsigned short)u;
}
// HW packed convert: dst = {bf16(lo), bf16(hi)}
__device__ __forceinline__ unsigned int cvtpk(float lo, float hi) {
    unsigned int r;
    asm("v_cvt_pk_bf16_f32 %0, %1, %2" : "=v"(r) : "v"(lo), "v"(hi));
    return r;
}
// XOR-swizzled byte offset within a 128B-row LDS tile (verified round 8)
__device__ __forceinline__ int swz128(int row, int colByte) {
    return row * 128 + (colByte ^ ((row & 7) << 4));
}

union s8u4 { s8 s; u4i u; };

// ---------------------------------------------------------------------------
// prepw: grid 80. Wb[320][256] bf16, fb[320] f32.  (round-13 passing)
// ---------------------------------------------------------------------------
__global__ __launch_bounds__(256) void prepw_kernel(
    const float* __restrict__ Wq, const float* __restrict__ bq,
    const float* __restrict__ Wk, const float* __restrict__ bk,
    const float* __restrict__ Wv, const float* __restrict__ bv,
    unsigned short* __restrict__ Wb, float* __restrict__ fb)
{
    const int t = threadIdx.x;
    #pragma unroll
    for (int i = 0; i < 4; ++i) {
        const int e = blockIdx.x * 1024 + i * 256 + t;
        const int u = e >> 8, c = e & 255;
        float val = (u < 32) ? Wq[u * 256 + c]
                  : (u < 64) ? Wk[(u - 32) * 256 + c]
                             : Wv[(u - 64) * 256 + c];
        Wb[e] = f2bf(val);
    }
    if (blockIdx.x == 0) {
        for (int u = t; u < MU; u += 256)
            fb[u] = (u < 32) ? bq[u] : (u < 64) ? bk[u - 32] : bv[u - 64];
    }
}

// ---------------------------------------------------------------------------
// projf: fused transpose + MFMA projection (round-13 passing, unchanged).
// ---------------------------------------------------------------------------
__global__ __launch_bounds__(256) void projf_kernel(
    const float* __restrict__ x, const unsigned short* __restrict__ Wb,
    const float* __restrict__ fb,
    unsigned short* __restrict__ qb, unsigned short* __restrict__ kb,
    unsigned short* __restrict__ vtb)
{
    __shared__ float xl[32][260];

    const int t   = threadIdx.x;
    const int b   = blockIdx.x >> 7;
    const int nbl = blockIdx.x & 127;
    const int n0  = nbl * 32;

    {
        const int nl = t & 7;
        const int c8 = t >> 3;
        #pragma unroll
        for (int pass = 0; pass < 8; ++pass) {
            const int c = c8 + pass * 32;
            f4 xv = *reinterpret_cast<const f4*>(x + ((size_t)(b * CC + c)) * NN + n0 + nl * 4);
            #pragma unroll
            for (int j = 0; j < 4; ++j) xl[nl * 4 + j][c] = xv[j];
        }
    }
    __syncthreads();

    const int w    = t >> 6;
    const int l    = t & 63;
    const int l15  = l & 15;
    const int g4   = l >> 4;
    const int nw   = w & 1;
    const int uw   = w >> 1;
    const int nloc = nw * 16 + l15;
    const int n    = n0 + nloc;

    s8 bfr[8];
    #pragma unroll
    for (int kk = 0; kk < 8; ++kk) {
        f4 a  = *reinterpret_cast<const f4*>(&xl[nloc][kk * 32 + g4 * 8]);
        f4 c2 = *reinterpret_cast<const f4*>(&xl[nloc][kk * 32 + g4 * 8 + 4]);
        s8u4 tmp;
        tmp.u = (u4i){ cvtpk(a[0], a[1]), cvtpk(a[2], a[3]),
                       cvtpk(c2[0], c2[1]), cvtpk(c2[2], c2[3]) };
        bfr[kk] = tmp.s;
    }

    const f4 z = {0.f, 0.f, 0.f, 0.f};
    unsigned short* qrow = qb + ((size_t)(b * NN + n)) * CO;
    unsigned short* krow = kb + ((size_t)(b * NN + n)) * CO;

    #pragma unroll
    for (int i = 0; i < 10; ++i) {
        const int u0 = (uw * 10 + i) * 16;
        f4 acc = z;
        #pragma unroll
        for (int kk = 0; kk < 8; ++kk) {
            s8 af = *reinterpret_cast<const s8*>(Wb + (size_t)(u0 + l15) * CC + kk * 32 + g4 * 8);
            acc = __builtin_amdgcn_mfma_f32_16x16x32_bf16(af, bfr[kk], acc, 0, 0, 0);
        }
        f4 bias4 = *reinterpret_cast<const f4*>(fb + u0 + g4 * 4);
        if (u0 < 32) {
            u2 pw = { cvtpk((acc[0] + bias4[0]) * LOG2E, (acc[1] + bias4[1]) * LOG2E),
                      cvtpk((acc[2] + bias4[2]) * LOG2E, (acc[3] + bias4[3]) * LOG2E) };
            *reinterpret_cast<u2*>(qrow + u0 + g4 * 4) = pw;
        } else if (u0 < 64) {
            u2 pw = { cvtpk(acc[0] + bias4[0], acc[1] + bias4[1]),
                      cvtpk(acc[2] + bias4[2], acc[3] + bias4[3]) };
            *reinterpret_cast<u2*>(krow + (u0 - 32) + g4 * 4) = pw;
        } else {
            const int cbase = u0 - 64 + g4 * 4;
            #pragma unroll
            for (int r = 0; r < 4; ++r)
                vtb[((size_t)(b * CC + cbase + r)) * NN + n] = f2bf(acc[r] + bias4[r]);
        }
    }
}

// ---------------------------------------------------------------------------
// colstats: civ = 1/sum_n exp2(S[n,m]) for 16 m; then emit SCALED V in MFMA
// B-fragment order (vfr):
//   16B chunk at ((mt*16+cg)*2+ksl)*512 + lane*8 holds
//   V'[m = mt*64 + ksl*32 + (lane>>4)*8 + e][c = cg*16 + (lane&15)].
// vtb stays unscaled (no in-place RMW).  grid 1024.
// ---------------------------------------------------------------------------
__global__ __launch_bounds__(256) void colstats_kernel(
    const unsigned short* __restrict__ qb, const unsigned short* __restrict__ kb,
    const unsigned short* __restrict__ vtb, unsigned short* __restrict__ vfr)
{
    __shared__ float red[4][16];
    __shared__ float civl[16];

    const int t   = threadIdx.x;
    const int b   = blockIdx.x >> 8;
    const int mb  = blockIdx.x & 255;
    const int l   = t & 63;
    const int w   = t >> 6;
    const int l15 = l & 15;
    const int g4  = l >> 4;
    const int m   = mb * 16 + l15;

    const unsigned short* qbB = qb + (size_t)b * NN * CO;
    s8 kfrag = *reinterpret_cast<const s8*>(kb + ((size_t)b * NN + m) * CO + g4 * 8);

    const f4 z = {0.f, 0.f, 0.f, 0.f};
    float ssum = 0.f;

    const int nbeg = w * 1024, nend = nbeg + 1024;
    for (int n0 = nbeg; n0 < nend; n0 += 32) {
        s8 a0 = *reinterpret_cast<const s8*>(qbB + (size_t)(n0 + l15) * CO + g4 * 8);
        s8 a1 = *reinterpret_cast<const s8*>(qbB + (size_t)(n0 + 16 + l15) * CO + g4 * 8);
        f4 d0 = __builtin_amdgcn_mfma_f32_16x16x32_bf16(a0, kfrag, z, 0, 0, 0);
        f4 d1 = __builtin_amdgcn_mfma_f32_16x16x32_bf16(a1, kfrag, z, 0, 0, 0);
        #pragma unroll
        for (int r = 0; r < 4; ++r) ssum += exp2f(d0[r]) + exp2f(d1[r]);
    }

    ssum += __shfl_xor(ssum, 16);
    ssum += __shfl_xor(ssum, 32);
    if (l < 16) red[w][l15] = ssum;
    __syncthreads();
    if (w == 0 && l < 16)
        civl[l15] = 1.0f / (red[0][l15] + red[1][l15] + red[2][l15] + red[3][l15]);
    __syncthreads();

    // emit scaled V fragments for m-slice mb*16..+16, c-row = t
    const int mt   = mb >> 2;
    const int ksl  = (mb >> 1) & 1;
    const int g4b  = (mb & 1) * 2;
    const int cg   = t >> 4;
    const int l15v = t & 15;
    const unsigned short* vp = vtb + ((size_t)(b * CC + t)) * NN + mb * 16;
    unsigned short* dst = vfr + (size_t)b * 1048576
                        + (((mt * 16 + cg) * 2 + ksl) << 9)
                        + (g4b * 16 + l15v) * 8;
    #pragma unroll
    for (int i = 0; i < 2; ++i) {
        us8 vv = *reinterpret_cast<const us8*>(vp + i * 8);
        u4i o;
        #pragma unroll
        for (int e2 = 0; e2 < 4; ++e2) {
            float f0 = __uint_as_float((unsigned int)vv[2 * e2]     << 16) * civl[i * 8 + 2 * e2];
            float f1 = __uint_as_float((unsigned int)vv[2 * e2 + 1] << 16) * civl[i * 8 + 2 * e2 + 1];
            o[e2] = cvtpk(f0, f1);
        }
        *reinterpret_cast<u4i*>(dst + i * 128) = o;
    }
}

// ---------------------------------------------------------------------------
// attn: out[n,c] = sum_m exp2(S[n,m]) * v'[m,c]  (v' pre-scaled, q pre-log2e).
// V NO LONGER TRANSITS LDS: vb B-frags loaded coalesced from vfr (fragment-
// ordered global layout), register double-buffered, prefetched 1 tile ahead.
// LDS holds only P (2 x 8 KB, swizzled).  64n x 128c, 512 thr, grid 512.
// ---------------------------------------------------------------------------
__global__ __launch_bounds__(512) void attn_kernel(
    const unsigned short* __restrict__ qb, const unsigned short* __restrict__ kb,
    const unsigned short* __restrict__ vfr, float* __restrict__ out)
{
    __shared__ __align__(16) char plds[2][64 * 128];    // P tile [n][m] bf16, swizzled

    const int t    = threadIdx.x;
    const int bid  = blockIdx.x;
    const int cblk = bid & 1;
    const int nblk = (bid >> 1) & 63;
    const int b    = bid >> 7;
    const int n0   = nblk * 64;
    const int c0   = cblk * 128;
    const int l    = t & 63;
    const int w    = t >> 6;        // 0..7
    const int l15  = l & 15;
    const int g4   = l >> 4;
    const int g    = w >> 1;        // S n-group (16 rows)
    const int p    = w & 1;         // S j-pair
    const int wrn  = w >> 2;        // PV n-half
    const int wcq  = w & 3;         // PV c-quarter

    const unsigned short* qbB = qb  + (size_t)b * NN * CO;
    const unsigned short* kbB = kb  + (size_t)b * NN * CO;

    // wave's 16 S-rows (B-operand of swapped MFMA)
    s8 qfrag = *reinterpret_cast<const s8*>(qbB + (size_t)(n0 + g * 16 + l15) * CO + g4 * 8);

    // ---- precomputed loop-invariant LDS byte offsets (P only) ----
    const int pw0  = swz128(g * 16 + l15, (2 * p) * 32 + g4 * 8);
    const int pw1  = swz128(g * 16 + l15, (2 * p + 1) * 32 + g4 * 8);
    const int prk0a0 = swz128(wrn * 32 +      l15,      g4 * 16);
    const int prk0a1 = swz128(wrn * 32 + 16 + l15,      g4 * 16);
    const int prk1a0 = swz128(wrn * 32 +      l15, 64 + g4 * 16);
    const int prk1a1 = swz128(wrn * 32 + 16 + l15, 64 + g4 * 16);

    // ---- incremental global pointers ----
    const unsigned short* kp  = kbB + (size_t)((2 * p) * 16 + l15) * CO + g4 * 8;
    // vfr base for this wave's c-quarter: cg = c0/16 + wcq*2 (+ci), lane-linear
    const unsigned short* vpf = vfr + (size_t)b * 1048576
                              + (size_t)((c0 >> 4) + wcq * 2) * 1024 + l * 8;

    s8 kreg[2];
    s8 vA0, vA1, vA2, vA3, vB0, vB1, vB2, vB3;   // (ci,ksl) = (0,0),(0,1),(1,0),(1,1)
    const f4 z = {0.f, 0.f, 0.f, 0.f};

#define LOADK() do { \
        kreg[0] = *reinterpret_cast<const s8*>(kp); \
        kreg[1] = *reinterpret_cast<const s8*>(kp + 16 * CO); \
        kp += 64 * CO; \
    } while (0)

#define LOADVB(V0, V1, V2, V3) do { \
        V0 = *reinterpret_cast<const s8*>(vpf); \
        V1 = *reinterpret_cast<const s8*>(vpf + 512); \
        V2 = *reinterpret_cast<const s8*>(vpf + 1024); \
        V3 = *reinterpret_cast<const s8*>(vpf + 1536); \
        vpf += 16384; \
    } while (0)

#define STAGE(BUF) do { \
        f4 d0 = __builtin_amdgcn_mfma_f32_16x16x32_bf16(kreg[0], qfrag, z, 0, 0, 0); \
        f4 d1 = __builtin_amdgcn_mfma_f32_16x16x32_bf16(kreg[1], qfrag, z, 0, 0, 0); \
        u2 pq0 = { cvtpk(exp2f(d0[0]), exp2f(d0[1])), cvtpk(exp2f(d0[2]), exp2f(d0[3])) }; \
        u2 pq1 = { cvtpk(exp2f(d1[0]), exp2f(d1[1])), cvtpk(exp2f(d1[2]), exp2f(d1[3])) }; \
        *reinterpret_cast<u2*>(plds[BUF] + pw0) = pq0; \
        *reinterpret_cast<u2*>(plds[BUF] + pw1) = pq1; \
    } while (0)

#define PVSTEP(BUF, V0, V1, V2, V3) do { \
        s8 pa00 = *reinterpret_cast<const s8*>(plds[BUF] + prk0a0); \
        s8 pa01 = *reinterpret_cast<const s8*>(plds[BUF] + prk0a1); \
        s8 pa10 = *reinterpret_cast<const s8*>(plds[BUF] + prk1a0); \
        s8 pa11 = *reinterpret_cast<const s8*>(plds[BUF] + prk1a1); \
        __builtin_amdgcn_s_setprio(1); \
        acc[0][0] = __builtin_amdgcn_mfma_f32_16x16x32_bf16(pa00, V0, acc[0][0], 0, 0, 0); \
        acc[0][1] = __builtin_amdgcn_mfma_f32_16x16x32_bf16(pa00, V2, acc[0][1], 0, 0, 0); \
        acc[1][0] = __builtin_amdgcn_mfma_f32_16x16x32_bf16(pa01, V0, acc[1][0], 0, 0, 0); \
        acc[1][1] = __builtin_amdgcn_mfma_f32_16x16x32_bf16(pa01, V2, acc[1][1], 0, 0, 0); \
        acc[0][0] = __builtin_amdgcn_mfma_f32_16x16x32_bf16(pa10, V1, acc[0][0], 0, 0, 0); \
        acc[0][1] = __builtin_amdgcn_mfma_f32_16x16x32_bf16(pa10, V3, acc[0][1], 0, 0, 0); \
        acc[1][0] = __builtin_amdgcn_mfma_f32_16x16x32_bf16(pa11, V1, acc[1][0], 0, 0, 0); \
        acc[1][1] = __builtin_amdgcn_mfma_f32_16x16x32_bf16(pa11, V3, acc[1][1], 0, 0, 0); \
        __builtin_amdgcn_s_setprio(0); \
    } while (0)

    f4 acc[2][2];
    acc[0][0] = z; acc[0][1] = z; acc[1][0] = z; acc[1][1] = z;

    // prologue: k/vb tile0, stage tile0; k/vb tile1
    LOADK();
    LOADVB(vA0, vA1, vA2, vA3);
    STAGE(0);
    LOADK();
    LOADVB(vB0, vB1, vB2, vB3);
    __syncthreads();

    for (int i = 0; i < 64; i += 2) {
        if (i < 63) {
            STAGE(1);
            if (i < 62) LOADK();
        }
        PVSTEP(0, vA0, vA1, vA2, vA3);
        if (i < 62) LOADVB(vA0, vA1, vA2, vA3);
        __syncthreads();

        if (i + 1 < 63) {
            STAGE(0);
            if (i + 1 < 62) LOADK();
        }
        PVSTEP(1, vB0, vB1, vB2, vB3);
        if (i + 1 < 62) LOADVB(vB0, vB1, vB2, vB3);
        __syncthreads();
    }

#undef LOADK
#undef LOADVB
#undef STAGE
#undef PVSTEP

    // D layout: col = lane&15 (c), row = g4*4 + r (n)
    #pragma unroll
    for (int a = 0; a < 2; ++a) {
        const int row = n0 + wrn * 32 + a * 16 + g4 * 4;
        #pragma unroll
        for (int c = 0; c < 2; ++c) {
            const int col = c0 + wcq * 32 + c * 16 + l15;
            #pragma unroll
            for (int r = 0; r < 4; ++r)
                out[((size_t)(b * NN + row + r)) * CC + col] = acc[a][c][r];
        }
    }
}

extern "C" void kernel_launch(void* const* d_in, const int* in_sizes, int n_in,
                              void* d_out, int out_size, void* d_ws, size_t ws_size,
                              hipStream_t stream)
{
    const float* x  = (const float*)d_in[0];
    const float* Wq = (const float*)d_in[1];
    const float* bq = (const float*)d_in[2];
    const float* Wk = (const float*)d_in[3];
    const float* bk = (const float*)d_in[4];
    const float* Wv = (const float*)d_in[5];
    const float* bv = (const float*)d_in[6];
    float* out = (float*)d_out;

    // ws layout: qb(1MB) | kb(1MB) | vtb(8MB) | vfr(8MB) | Wb(160KB) | fb
    unsigned short* qb  = (unsigned short*)d_ws;
    unsigned short* kb  = qb  + (size_t)NB * NN * CO;
    unsigned short* vtb = kb  + (size_t)NB * NN * CO;
    unsigned short* vfr = vtb + (size_t)NB * CC * NN;
    unsigned short* Wb  = vfr + (size_t)NB * CC * NN;
    float*          fb  = (float*)(Wb + (size_t)MU * CC);

    prepw_kernel<<<dim3(80), dim3(256), 0, stream>>>(Wq, bq, Wk, bk, Wv, bv, Wb, fb);
    projf_kernel<<<dim3(512), dim3(256), 0, stream>>>(x, Wb, fb, qb, kb, vtb);
    colstats_kernel<<<dim3(1024), dim3(256), 0, stream>>>(qb, kb, vtb, vfr);
    attn_kernel<<<dim3(512), dim3(512), 0, stream>>>(qb, kb, vfr, out);
}

// Round 18
// 122.219 us; speedup vs baseline: 1.0986x; 1.0009x over previous
//
#include <hip/hip_runtime.h>
#include <math.h>

#define NB 4
#define CC 256
#define CO 32
#define NN 4096
#define MU 320   // concat projection rows: 32 q + 32 k + 256 v
#define LOG2E 1.44269504088896f

typedef __attribute__((ext_vector_type(4))) float f4;
typedef __attribute__((ext_vector_type(8))) short s8;          // 8 bf16 MFMA frag
typedef __attribute__((ext_vector_type(8))) unsigned short us8;
typedef __attribute__((ext_vector_type(2))) unsigned int u2;
typedef __attribute__((ext_vector_type(4))) unsigned int u4i;

// fp32 -> bf16 (RNE), scalar fallback
__device__ __forceinline__ unsigned short f2bf(float f) {
    unsigned int u = __float_as_uint(f);
    u = (u + 0x7FFFu + ((u >> 16) & 1u)) >> 16;
    return (unsigned short)u;
}
// HW packed convert: dst = {bf16(lo), bf16(hi)}
__device__ __forceinline__ unsigned int cvtpk(float lo, float hi) {
    unsigned int r;
    asm("v_cvt_pk_bf16_f32 %0, %1, %2" : "=v"(r) : "v"(lo), "v"(hi));
    return r;
}
// XOR-swizzled byte offset within a 128B-row LDS tile (verified round 8)
__device__ __forceinline__ int swz128(int row, int colByte) {
    return row * 128 + (colByte ^ ((row & 7) << 4));
}
// Barrier that drains ONLY LDS ops (lgkmcnt), leaving global loads in flight.
// (HIP's __syncthreads emits s_waitcnt vmcnt(0) lgkmcnt(0) -- that vmcnt(0)
//  drain was costing ~500 cyc/tile once vb prefetch moved to global loads.)
#define LDS_BARRIER() asm volatile("s_waitcnt lgkmcnt(0)\n\ts_barrier" ::: "memory")

union s8u4 { s8 s; u4i u; };

// ---------------------------------------------------------------------------
// prepw: grid 80. Wb[320][256] bf16, fb[320] f32.  (round-17 passing)
// ---------------------------------------------------------------------------
__global__ __launch_bounds__(256) void prepw_kernel(
    const float* __restrict__ Wq, const float* __restrict__ bq,
    const float* __restrict__ Wk, const float* __restrict__ bk,
    const float* __restrict__ Wv, const float* __restrict__ bv,
    unsigned short* __restrict__ Wb, float* __restrict__ fb)
{
    const int t = threadIdx.x;
    #pragma unroll
    for (int i = 0; i < 4; ++i) {
        const int e = blockIdx.x * 1024 + i * 256 + t;
        const int u = e >> 8, c = e & 255;
        float val = (u < 32) ? Wq[u * 256 + c]
                  : (u < 64) ? Wk[(u - 32) * 256 + c]
                             : Wv[(u - 64) * 256 + c];
        Wb[e] = f2bf(val);
    }
    if (blockIdx.x == 0) {
        for (int u = t; u < MU; u += 256)
            fb[u] = (u < 32) ? bq[u] : (u < 64) ? bk[u - 32] : bv[u - 64];
    }
}

// ---------------------------------------------------------------------------
// projf: fused transpose + MFMA projection (round-17 passing, unchanged).
// ---------------------------------------------------------------------------
__global__ __launch_bounds__(256) void projf_kernel(
    const float* __restrict__ x, const unsigned short* __restrict__ Wb,
    const float* __restrict__ fb,
    unsigned short* __restrict__ qb, unsigned short* __restrict__ kb,
    unsigned short* __restrict__ vtb)
{
    __shared__ float xl[32][260];

    const int t   = threadIdx.x;
    const int b   = blockIdx.x >> 7;
    const int nbl = blockIdx.x & 127;
    const int n0  = nbl * 32;

    {
        const int nl = t & 7;
        const int c8 = t >> 3;
        #pragma unroll
        for (int pass = 0; pass < 8; ++pass) {
            const int c = c8 + pass * 32;
            f4 xv = *reinterpret_cast<const f4*>(x + ((size_t)(b * CC + c)) * NN + n0 + nl * 4);
            #pragma unroll
            for (int j = 0; j < 4; ++j) xl[nl * 4 + j][c] = xv[j];
        }
    }
    __syncthreads();

    const int w    = t >> 6;
    const int l    = t & 63;
    const int l15  = l & 15;
    const int g4   = l >> 4;
    const int nw   = w & 1;
    const int uw   = w >> 1;
    const int nloc = nw * 16 + l15;
    const int n    = n0 + nloc;

    s8 bfr[8];
    #pragma unroll
    for (int kk = 0; kk < 8; ++kk) {
        f4 a  = *reinterpret_cast<const f4*>(&xl[nloc][kk * 32 + g4 * 8]);
        f4 c2 = *reinterpret_cast<const f4*>(&xl[nloc][kk * 32 + g4 * 8 + 4]);
        s8u4 tmp;
        tmp.u = (u4i){ cvtpk(a[0], a[1]), cvtpk(a[2], a[3]),
                       cvtpk(c2[0], c2[1]), cvtpk(c2[2], c2[3]) };
        bfr[kk] = tmp.s;
    }

    const f4 z = {0.f, 0.f, 0.f, 0.f};
    unsigned short* qrow = qb + ((size_t)(b * NN + n)) * CO;
    unsigned short* krow = kb + ((size_t)(b * NN + n)) * CO;

    #pragma unroll
    for (int i = 0; i < 10; ++i) {
        const int u0 = (uw * 10 + i) * 16;
        f4 acc = z;
        #pragma unroll
        for (int kk = 0; kk < 8; ++kk) {
            s8 af = *reinterpret_cast<const s8*>(Wb + (size_t)(u0 + l15) * CC + kk * 32 + g4 * 8);
            acc = __builtin_amdgcn_mfma_f32_16x16x32_bf16(af, bfr[kk], acc, 0, 0, 0);
        }
        f4 bias4 = *reinterpret_cast<const f4*>(fb + u0 + g4 * 4);
        if (u0 < 32) {
            u2 pw = { cvtpk((acc[0] + bias4[0]) * LOG2E, (acc[1] + bias4[1]) * LOG2E),
                      cvtpk((acc[2] + bias4[2]) * LOG2E, (acc[3] + bias4[3]) * LOG2E) };
            *reinterpret_cast<u2*>(qrow + u0 + g4 * 4) = pw;
        } else if (u0 < 64) {
            u2 pw = { cvtpk(acc[0] + bias4[0], acc[1] + bias4[1]),
                      cvtpk(acc[2] + bias4[2], acc[3] + bias4[3]) };
            *reinterpret_cast<u2*>(krow + (u0 - 32) + g4 * 4) = pw;
        } else {
            const int cbase = u0 - 64 + g4 * 4;
            #pragma unroll
            for (int r = 0; r < 4; ++r)
                vtb[((size_t)(b * CC + cbase + r)) * NN + n] = f2bf(acc[r] + bias4[r]);
        }
    }
}

// ---------------------------------------------------------------------------
// colstats: civ = 1/sum_n exp2(S[n,m]) for 16 m; then emit SCALED V in MFMA
// B-fragment order (vfr).  (round-17 passing, unchanged)
// ---------------------------------------------------------------------------
__global__ __launch_bounds__(256) void colstats_kernel(
    const unsigned short* __restrict__ qb, const unsigned short* __restrict__ kb,
    const unsigned short* __restrict__ vtb, unsigned short* __restrict__ vfr)
{
    __shared__ float red[4][16];
    __shared__ float civl[16];

    const int t   = threadIdx.x;
    const int b   = blockIdx.x >> 8;
    const int mb  = blockIdx.x & 255;
    const int l   = t & 63;
    const int w   = t >> 6;
    const int l15 = l & 15;
    const int g4  = l >> 4;
    const int m   = mb * 16 + l15;

    const unsigned short* qbB = qb + (size_t)b * NN * CO;
    s8 kfrag = *reinterpret_cast<const s8*>(kb + ((size_t)b * NN + m) * CO + g4 * 8);

    const f4 z = {0.f, 0.f, 0.f, 0.f};
    float ssum = 0.f;

    const int nbeg = w * 1024, nend = nbeg + 1024;
    for (int n0 = nbeg; n0 < nend; n0 += 32) {
        s8 a0 = *reinterpret_cast<const s8*>(qbB + (size_t)(n0 + l15) * CO + g4 * 8);
        s8 a1 = *reinterpret_cast<const s8*>(qbB + (size_t)(n0 + 16 + l15) * CO + g4 * 8);
        f4 d0 = __builtin_amdgcn_mfma_f32_16x16x32_bf16(a0, kfrag, z, 0, 0, 0);
        f4 d1 = __builtin_amdgcn_mfma_f32_16x16x32_bf16(a1, kfrag, z, 0, 0, 0);
        #pragma unroll
        for (int r = 0; r < 4; ++r) ssum += exp2f(d0[r]) + exp2f(d1[r]);
    }

    ssum += __shfl_xor(ssum, 16);
    ssum += __shfl_xor(ssum, 32);
    if (l < 16) red[w][l15] = ssum;
    __syncthreads();
    if (w == 0 && l < 16)
        civl[l15] = 1.0f / (red[0][l15] + red[1][l15] + red[2][l15] + red[3][l15]);
    __syncthreads();

    // emit scaled V fragments for m-slice mb*16..+16, c-row = t
    const int mt   = mb >> 2;
    const int ksl  = (mb >> 1) & 1;
    const int g4b  = (mb & 1) * 2;
    const int cg   = t >> 4;
    const int l15v = t & 15;
    const unsigned short* vp = vtb + ((size_t)(b * CC + t)) * NN + mb * 16;
    unsigned short* dst = vfr + (size_t)b * 1048576
                        + (((mt * 16 + cg) * 2 + ksl) << 9)
                        + (g4b * 16 + l15v) * 8;
    #pragma unroll
    for (int i = 0; i < 2; ++i) {
        us8 vv = *reinterpret_cast<const us8*>(vp + i * 8);
        u4i o;
        #pragma unroll
        for (int e2 = 0; e2 < 4; ++e2) {
            float f0 = __uint_as_float((unsigned int)vv[2 * e2]     << 16) * civl[i * 8 + 2 * e2];
            float f1 = __uint_as_float((unsigned int)vv[2 * e2 + 1] << 16) * civl[i * 8 + 2 * e2 + 1];
            o[e2] = cvtpk(f0, f1);
        }
        *reinterpret_cast<u4i*>(dst + i * 128) = o;
    }
}

// ---------------------------------------------------------------------------
// attn: round-17 structure (V from vfr in registers, LDS = P only) with ONE
// change: __syncthreads -> LDS_BARRIER (lgkmcnt-only drain + raw s_barrier),
// so k/vb global prefetch loads stay IN FLIGHT across the per-tile barriers.
// Cross-wave dependency is only the P tile in LDS -> lgkmcnt(0) suffices.
// ---------------------------------------------------------------------------
__global__ __launch_bounds__(512) void attn_kernel(
    const unsigned short* __restrict__ qb, const unsigned short* __restrict__ kb,
    const unsigned short* __restrict__ vfr, float* __restrict__ out)
{
    __shared__ __align__(16) char plds[2][64 * 128];    // P tile [n][m] bf16, swizzled

    const int t    = threadIdx.x;
    const int bid  = blockIdx.x;
    const int cblk = bid & 1;
    const int nblk = (bid >> 1) & 63;
    const int b    = bid >> 7;
    const int n0   = nblk * 64;
    const int c0   = cblk * 128;
    const int l    = t & 63;
    const int w    = t >> 6;        // 0..7
    const int l15  = l & 15;
    const int g4   = l >> 4;
    const int g    = w >> 1;        // S n-group (16 rows)
    const int p    = w & 1;         // S j-pair
    const int wrn  = w >> 2;        // PV n-half
    const int wcq  = w & 3;         // PV c-quarter

    const unsigned short* qbB = qb  + (size_t)b * NN * CO;
    const unsigned short* kbB = kb  + (size_t)b * NN * CO;

    // wave's 16 S-rows (B-operand of swapped MFMA)
    s8 qfrag = *reinterpret_cast<const s8*>(qbB + (size_t)(n0 + g * 16 + l15) * CO + g4 * 8);

    // ---- precomputed loop-invariant LDS byte offsets (P only) ----
    const int pw0  = swz128(g * 16 + l15, (2 * p) * 32 + g4 * 8);
    const int pw1  = swz128(g * 16 + l15, (2 * p + 1) * 32 + g4 * 8);
    const int prk0a0 = swz128(wrn * 32 +      l15,      g4 * 16);
    const int prk0a1 = swz128(wrn * 32 + 16 + l15,      g4 * 16);
    const int prk1a0 = swz128(wrn * 32 +      l15, 64 + g4 * 16);
    const int prk1a1 = swz128(wrn * 32 + 16 + l15, 64 + g4 * 16);

    // ---- incremental global pointers ----
    const unsigned short* kp  = kbB + (size_t)((2 * p) * 16 + l15) * CO + g4 * 8;
    const unsigned short* vpf = vfr + (size_t)b * 1048576
                              + (size_t)((c0 >> 4) + wcq * 2) * 1024 + l * 8;

    s8 kreg[2];
    s8 vA0, vA1, vA2, vA3, vB0, vB1, vB2, vB3;   // (ci,ksl) = (0,0),(0,1),(1,0),(1,1)
    const f4 z = {0.f, 0.f, 0.f, 0.f};

#define LOADK() do { \
        kreg[0] = *reinterpret_cast<const s8*>(kp); \
        kreg[1] = *reinterpret_cast<const s8*>(kp + 16 * CO); \
        kp += 64 * CO; \
    } while (0)

#define LOADVB(V0, V1, V2, V3) do { \
        V0 = *reinterpret_cast<const s8*>(vpf); \
        V1 = *reinterpret_cast<const s8*>(vpf + 512); \
        V2 = *reinterpret_cast<const s8*>(vpf + 1024); \
        V3 = *reinterpret_cast<const s8*>(vpf + 1536); \
        vpf += 16384; \
    } while (0)

#define STAGE(BUF) do { \
        f4 d0 = __builtin_amdgcn_mfma_f32_16x16x32_bf16(kreg[0], qfrag, z, 0, 0, 0); \
        f4 d1 = __builtin_amdgcn_mfma_f32_16x16x32_bf16(kreg[1], qfrag, z, 0, 0, 0); \
        u2 pq0 = { cvtpk(exp2f(d0[0]), exp2f(d0[1])), cvtpk(exp2f(d0[2]), exp2f(d0[3])) }; \
        u2 pq1 = { cvtpk(exp2f(d1[0]), exp2f(d1[1])), cvtpk(exp2f(d1[2]), exp2f(d1[3])) }; \
        *reinterpret_cast<u2*>(plds[BUF] + pw0) = pq0; \
        *reinterpret_cast<u2*>(plds[BUF] + pw1) = pq1; \
    } while (0)

#define PVSTEP(BUF, V0, V1, V2, V3) do { \
        s8 pa00 = *reinterpret_cast<const s8*>(plds[BUF] + prk0a0); \
        s8 pa01 = *reinterpret_cast<const s8*>(plds[BUF] + prk0a1); \
        s8 pa10 = *reinterpret_cast<const s8*>(plds[BUF] + prk1a0); \
        s8 pa11 = *reinterpret_cast<const s8*>(plds[BUF] + prk1a1); \
        __builtin_amdgcn_s_setprio(1); \
        acc[0][0] = __builtin_amdgcn_mfma_f32_16x16x32_bf16(pa00, V0, acc[0][0], 0, 0, 0); \
        acc[0][1] = __builtin_amdgcn_mfma_f32_16x16x32_bf16(pa00, V2, acc[0][1], 0, 0, 0); \
        acc[1][0] = __builtin_amdgcn_mfma_f32_16x16x32_bf16(pa01, V0, acc[1][0], 0, 0, 0); \
        acc[1][1] = __builtin_amdgcn_mfma_f32_16x16x32_bf16(pa01, V2, acc[1][1], 0, 0, 0); \
        acc[0][0] = __builtin_amdgcn_mfma_f32_16x16x32_bf16(pa10, V1, acc[0][0], 0, 0, 0); \
        acc[0][1] = __builtin_amdgcn_mfma_f32_16x16x32_bf16(pa10, V3, acc[0][1], 0, 0, 0); \
        acc[1][0] = __builtin_amdgcn_mfma_f32_16x16x32_bf16(pa11, V1, acc[1][0], 0, 0, 0); \
        acc[1][1] = __builtin_amdgcn_mfma_f32_16x16x32_bf16(pa11, V3, acc[1][1], 0, 0, 0); \
        __builtin_amdgcn_s_setprio(0); \
    } while (0)

    f4 acc[2][2];
    acc[0][0] = z; acc[0][1] = z; acc[1][0] = z; acc[1][1] = z;

    // prologue: k/vb tile0, stage tile0; k/vb tile1
    LOADK();
    LOADVB(vA0, vA1, vA2, vA3);
    STAGE(0);
    LOADK();
    LOADVB(vB0, vB1, vB2, vB3);
    LDS_BARRIER();

    for (int i = 0; i < 64; i += 2) {
        if (i < 63) {
            STAGE(1);
            if (i < 62) LOADK();
        }
        PVSTEP(0, vA0, vA1, vA2, vA3);
        if (i < 62) LOADVB(vA0, vA1, vA2, vA3);
        LDS_BARRIER();

        if (i + 1 < 63) {
            STAGE(0);
            if (i + 1 < 62) LOADK();
        }
        PVSTEP(1, vB0, vB1, vB2, vB3);
        if (i + 1 < 62) LOADVB(vB0, vB1, vB2, vB3);
        LDS_BARRIER();
    }

#undef LOADK
#undef LOADVB
#undef STAGE
#undef PVSTEP

    // D layout: col = lane&15 (c), row = g4*4 + r (n)
    #pragma unroll
    for (int a = 0; a < 2; ++a) {
        const int row = n0 + wrn * 32 + a * 16 + g4 * 4;
        #pragma unroll
        for (int c = 0; c < 2; ++c) {
            const int col = c0 + wcq * 32 + c * 16 + l15;
            #pragma unroll
            for (int r = 0; r < 4; ++r)
                out[((size_t)(b * NN + row + r)) * CC + col] = acc[a][c][r];
        }
    }
}

extern "C" void kernel_launch(void* const* d_in, const int* in_sizes, int n_in,
                              void* d_out, int out_size, void* d_ws, size_t ws_size,
                              hipStream_t stream)
{
    const float* x  = (const float*)d_in[0];
    const float* Wq = (const float*)d_in[1];
    const float* bq = (const float*)d_in[2];
    const float* Wk = (const float*)d_in[3];
    const float* bk = (const float*)d_in[4];
    const float* Wv = (const float*)d_in[5];
    const float* bv = (const float*)d_in[6];
    float* out = (float*)d_out;

    // ws layout: qb(1MB) | kb(1MB) | vtb(8MB) | vfr(8MB) | Wb(160KB) | fb
    unsigned short* qb  = (unsigned short*)d_ws;
    unsigned short* kb  = qb  + (size_t)NB * NN * CO;
    unsigned short* vtb = kb  + (size_t)NB * NN * CO;
    unsigned short* vfr = vtb + (size_t)NB * CC * NN;
    unsigned short* Wb  = vfr + (size_t)NB * CC * NN;
    float*          fb  = (float*)(Wb + (size_t)MU * CC);

    prepw_kernel<<<dim3(80), dim3(256), 0, stream>>>(Wq, bq, Wk, bk, Wv, bv, Wb, fb);
    projf_kernel<<<dim3(512), dim3(256), 0, stream>>>(x, Wb, fb, qb, kb, vtb);
    colstats_kernel<<<dim3(1024), dim3(256), 0, stream>>>(qb, kb, vtb, vfr);
    attn_kernel<<<dim3(512), dim3(512), 0, stream>>>(qb, kb, vfr, out);
}